// Round 4
// baseline (565.593 us; speedup 1.0000x reference)
//
#include <hip/hip_runtime.h>
#include <hip/hip_bf16.h>
#include <math.h>

// ---------------------------------------------------------------------------
// GCNWithEdge, algebraically folded + bucketed CSR gather. FP32 in/out.
//   xWs[n]   = dinv[n] * (x @ W1)[n]          (bf16, dinv folded in)
//   h1[n]    = relu(dinv[n]*(sum_{s->n} xWs[s] + xWs[n]) + b1)
//   Qs[n][c] = dinv[n] * (h1[n] . U[:,c]),  U = W2 @ fcW1[0:64,:]
//   P[n][c]  = dinv[n] * (sum_{s->n} Qs[s][c] + Qs[n][c])
//   z[e][c]  = P[s]-P[d] + a0*fcW1[64,c] + a1*fcW1[65,c] + E0t[a2]+E1t[a3]+fcb1
//   out = log_softmax( relu(z) @ fcW2 + fcb2 )
// R15: R14's 6-kernel fusion retried with a CAPTURE-SAFE grid barrier.
// R14's hipLaunchCooperativeKernel died inside the harness's graph capture
// (launch no-ops -> gather1 reads garbage rp -> hang). Replacement: device-
// scope atomic spin barrier. Deadlock-free by capacity: 256 blocks (= CUs),
// 33.3KB LDS, ~64 VGPR -> every CU hosts >=4 blocks, so all blocks resident
// unconditionally; device-scope atomics are XCD-coherent. Barrier flags are
// zeroed per replay by a 32B hipMemsetAsync (ws is re-poisoned between
// iterations; R12 proved memsetAsync is capture-legal). __threadfence on
// both sides of each barrier for cross-XCD L2 visibility.
// Pipeline: memset + k_build + gather1 + gather2 + edge = 5 dispatches vs 9
// (audit: ~10-12us bubble per boundary across R11/R12/R13).
// Phase bodies verbatim from R11's proven kernels; gather1/gather2/edge
// byte-identical to R11 (254us).
// ---------------------------------------------------------------------------

typedef __hip_bfloat16 bf16;
#define NBLK 256          // fused grid size; also the scan chunk count

// ---- capture-safe grid barrier: all NBLK blocks arrive, then proceed ----
__device__ __forceinline__ void gbar(int* flag) {
    __syncthreads();
    __threadfence();                               // release: flush block's writes
    if (threadIdx.x == 0) {
        atomicAdd(flag, 1);
        while (atomicAdd(flag, 0) < NBLK)          // device-scope coherent read
            __builtin_amdgcn_s_sleep(2);
    }
    __syncthreads();
    __threadfence();                               // acquire: invalidate stale lines
}

// ---- fused CSR build + tiny tables + gemm1 (NBLK blocks, spin barriers) ----
__global__ __launch_bounds__(256) void k_build(
        const int* __restrict__ src, const int* __restrict__ dst,
        const float* __restrict__ x, const float* __restrict__ W1,
        const float* __restrict__ W2,
        const float* __restrict__ emb0, const float* __restrict__ emb1,
        const float* __restrict__ fcW1, const float* __restrict__ fcb1,
        const float* __restrict__ fcW2, const float* __restrict__ fcb2,
        int* __restrict__ cntm, int* __restrict__ part,
        float* __restrict__ U, float* __restrict__ E0t,
        float* __restrict__ E1t, float* __restrict__ C,
        int* __restrict__ pairs, int* __restrict__ col,
        int* __restrict__ rp, float* __restrict__ dinv,
        bf16* __restrict__ xWs, int* __restrict__ flags,
        int N, int E, int NB, int chunk) {
    __shared__ __align__(16) union {
        struct { int h[512]; } p1;                     // kA histogram
        struct { int s[256]; } p2;                     // mscan row
        struct { int s[256]; } p3;                     // part scan
        struct { int off[512]; } p4;                   // kB cursors
        struct { int cnt[256]; int s[256]; } p5;       // kC
        struct { float xs[64][66]; float Ws[64][64]; } p6;  // gemm tile
    } sh;
    const int b = blockIdx.x;
    const int t = threadIdx.x;
    const int lo = b * chunk, hi = min(E, lo + chunk);

    // ---- P1: per-(bucket,block) histogram (kA) ----
    for (int i = t; i < NB; i += 256) sh.p1.h[i] = 0;
    __syncthreads();
    for (int e = lo + t; e < hi; e += 256)
        atomicAdd(&sh.p1.h[dst[e] >> 8], 1);
    __syncthreads();
    for (int i = t; i < NB; i += 256)
        cntm[(size_t)i * NBLK + b] = sh.p1.h[i];

    gbar(flags + 0);

    // ---- P2: local exclusive scan of each cntm row (mscan) + tiny tables ----
    for (int r = b; r < NB; r += NBLK) {
        int idx = (r << 8) + t;
        int v = cntm[idx];
        sh.p2.s[t] = v;
        int xx = v;
        for (int off = 1; off < 256; off <<= 1) {
            __syncthreads();
            int add = (t >= off) ? sh.p2.s[t - off] : 0;
            __syncthreads();
            xx += add;
            sh.p2.s[t] = xx;
        }
        cntm[idx] = xx - v;
        if (t == 255) part[r] = xx;                    // row total
        __syncthreads();
    }
    if (b == 192) {                                    // U = W2 @ fcW1[0:64,:]
        if (t < 128) {
            int i = t >> 1, c = t & 1;
            float sum = 0.f;
            for (int j = 0; j < 64; ++j) sum += W2[i * 64 + j] * fcW1[j * 2 + c];
            U[i * 2 + c] = sum;
        }
    } else if (b == 193) {                             // embedding tables
        if (t < 40) {
            int i = t >> 1, c = t & 1;
            float s0 = 0.f, s1 = 0.f;
            for (int k = 0; k < 32; ++k) {
                s0 += emb0[i * 32 + k] * fcW1[(66 + k) * 2 + c];
                s1 += emb1[i * 32 + k] * fcW1[(98 + k) * 2 + c];
            }
            E0t[i * 2 + c] = s0;
            E1t[i * 2 + c] = s1;
        }
    } else if (b == 194) {                             // b2 cancels in h2[s]-h2[d]
        if (t == 0) {
            C[0] = fcb1[0];  C[1] = fcb1[1];
            C[2] = fcW1[128]; C[3] = fcW1[129];
            C[4] = fcW1[130]; C[5] = fcW1[131];
            C[6] = fcW2[0];  C[7] = fcW2[1];
            C[8] = fcW2[2];  C[9] = fcW2[3];
            C[10] = fcb2[0]; C[11] = fcb2[1];
        }
    }

    gbar(flags + 1);

    // ---- P3: exclusive scan of part[0..NB) (block 0; NB <= 512) ----
    if (b == 0) {
        int v2 = (256 + t < NB) ? part[256 + t] : 0;   // chunk2 read (disjoint)
        int v1 = (t < NB) ? part[t] : 0;
        sh.p3.s[t] = v1;
        int x1 = v1;
        for (int off = 1; off < 256; off <<= 1) {
            __syncthreads();
            int add = (t >= off) ? sh.p3.s[t - off] : 0;
            __syncthreads();
            x1 += add;
            sh.p3.s[t] = x1;
        }
        __syncthreads();
        int tot1 = sh.p3.s[255];
        if (t < NB) part[t] = x1 - v1;
        __syncthreads();
        sh.p3.s[t] = v2;
        int x2 = v2;
        for (int off = 1; off < 256; off <<= 1) {
            __syncthreads();
            int add = (t >= off) ? sh.p3.s[t - off] : 0;
            __syncthreads();
            x2 += add;
            sh.p3.s[t] = x2;
        }
        if (256 + t < NB) part[256 + t] = tot1 + (x2 - v2);
    }

    gbar(flags + 2);

    // ---- P4: place packed pairs (kB) ----
    for (int i = t; i < NB; i += 256)
        sh.p4.off[i] = cntm[(size_t)i * NBLK + b] + part[i];
    __syncthreads();
    for (int e = lo + t; e < hi; e += 256) {
        int d = dst[e];
        int pos = atomicAdd(&sh.p4.off[d >> 8], 1);
        pairs[pos] = ((d & 255) << 17) | src[e];
    }

    gbar(flags + 3);

    // ---- P5: per-bucket CSR finalize (kC), buckets round-robin ----
    for (int bb = b; bb < NB; bb += NBLK) {
        __syncthreads();                               // protect LDS reuse
        int n0 = bb << 8;
        int nn = min(256, N - n0);
        int base = part[bb];
        int end  = (bb == NB - 1) ? E : part[bb + 1];
        sh.p5.cnt[t] = 0;
        __syncthreads();
        for (int j = base + t; j < end; j += 256)
            atomicAdd(&sh.p5.cnt[pairs[j] >> 17], 1);
        __syncthreads();
        int v = sh.p5.cnt[t];
        if (t < nn) dinv[n0 + t] = rsqrtf((float)v + 1.0f);   // +1 self-loop
        sh.p5.s[t] = v;
        int xx = v;
        for (int off = 1; off < 256; off <<= 1) {
            __syncthreads();
            int add = (t >= off) ? sh.p5.s[t - off] : 0;
            __syncthreads();
            xx += add;
            sh.p5.s[t] = xx;
        }
        __syncthreads();
        int excl = xx - v;
        if (t < nn) rp[n0 + t] = base + excl;
        sh.p5.cnt[t] = base + excl;                    // cursor
        __syncthreads();
        for (int j = base + t; j < end; j += 256) {
            int v2 = pairs[j];
            int pos = atomicAdd(&sh.p5.cnt[v2 >> 17], 1);
            col[pos] = v2 & 0x1FFFF;
        }
        if (bb == NB - 1 && t == 0) rp[N] = E;
    }

    gbar(flags + 4);

    // ---- P6: xWs = dinv * (x @ W1), grid-stride tiles (gemm1) ----
    int ntiles = (N + 63) >> 6;
    for (int tile = b; tile < ntiles; tile += NBLK) {
        __syncthreads();                               // protect LDS reuse
        int n0 = tile << 6;
        for (int i = t; i < 4096; i += 256) sh.p6.Ws[i >> 6][i & 63] = W1[i];
        for (int i = t; i < 4096; i += 256) {
            int node = i >> 6, k = i & 63;
            float v = (n0 + node < N) ? x[(size_t)(n0 + node) * 64 + k] : 0.f;
            sh.p6.xs[k][node] = v;
        }
        __syncthreads();
        int tr = t >> 4;
        int tc = t & 15;
        float acc[4][4] = {};
#pragma unroll 8
        for (int k = 0; k < 64; ++k) {
            float2 xa = *(const float2*)&sh.p6.xs[k][tr * 4];
            float2 xb = *(const float2*)&sh.p6.xs[k][tr * 4 + 2];
            float4 wv = *(const float4*)&sh.p6.Ws[k][tc * 4];
            acc[0][0] = fmaf(xa.x, wv.x, acc[0][0]);
            acc[0][1] = fmaf(xa.x, wv.y, acc[0][1]);
            acc[0][2] = fmaf(xa.x, wv.z, acc[0][2]);
            acc[0][3] = fmaf(xa.x, wv.w, acc[0][3]);
            acc[1][0] = fmaf(xa.y, wv.x, acc[1][0]);
            acc[1][1] = fmaf(xa.y, wv.y, acc[1][1]);
            acc[1][2] = fmaf(xa.y, wv.z, acc[1][2]);
            acc[1][3] = fmaf(xa.y, wv.w, acc[1][3]);
            acc[2][0] = fmaf(xb.x, wv.x, acc[2][0]);
            acc[2][1] = fmaf(xb.x, wv.y, acc[2][1]);
            acc[2][2] = fmaf(xb.x, wv.z, acc[2][2]);
            acc[2][3] = fmaf(xb.x, wv.w, acc[2][3]);
            acc[3][0] = fmaf(xb.y, wv.x, acc[3][0]);
            acc[3][1] = fmaf(xb.y, wv.y, acc[3][1]);
            acc[3][2] = fmaf(xb.y, wv.z, acc[3][2]);
            acc[3][3] = fmaf(xb.y, wv.w, acc[3][3]);
        }
#pragma unroll
        for (int i = 0; i < 4; ++i) {
            int node = n0 + tr * 4 + i;
            if (node < N) {
                float di = dinv[node];
                __hip_bfloat162 p0, p1;
                p0.x = __float2bfloat16(di * acc[i][0]);
                p0.y = __float2bfloat16(di * acc[i][1]);
                p1.x = __float2bfloat16(di * acc[i][2]);
                p1.y = __float2bfloat16(di * acc[i][3]);
                __hip_bfloat162* dst2 = (__hip_bfloat162*)&xWs[(size_t)node * 64 + tc * 4];
                dst2[0] = p0;
                dst2[1] = p1;
            }
        }
    }
}

// ---- conv1 gather: 32 lanes/node, bf16x2/lane, 2 nodes per wave ----
__global__ __launch_bounds__(256) void k_gather1(
        const bf16* __restrict__ xWs, const float* __restrict__ dinv,
        const int* __restrict__ rp, const int* __restrict__ col,
        const float* __restrict__ b1, const float* __restrict__ U,
        float* __restrict__ Qs, int N, int E) {
    int wid = blockIdx.x * 8 + (threadIdx.x >> 5);   // node id (8 per block)
    int c = threadIdx.x & 31;                        // channel pair: 2c, 2c+1
    if (wid >= N) return;
    const __hip_bfloat162* xW2 = (const __hip_bfloat162*)xWs;  // [n*32 + c]
    __hip_bfloat162 sv = xW2[(size_t)wid * 32 + c];
    float ax = __bfloat162float(sv.x);
    float ay = __bfloat162float(sv.y);
    int beg = rp[wid], end = rp[wid + 1];
    for (int base = beg; base < end; base += 32) {
        int nn = min(32, end - base);
        int colv = col[min(base + c, E - 1)];
        int jj = 0;
        for (; jj + 8 <= nn; jj += 8) {
            int m0 = __shfl(colv, jj + 0, 32);
            int m1 = __shfl(colv, jj + 1, 32);
            int m2 = __shfl(colv, jj + 2, 32);
            int m3 = __shfl(colv, jj + 3, 32);
            int m4 = __shfl(colv, jj + 4, 32);
            int m5 = __shfl(colv, jj + 5, 32);
            int m6 = __shfl(colv, jj + 6, 32);
            int m7 = __shfl(colv, jj + 7, 32);
            __hip_bfloat162 v0 = xW2[(size_t)m0 * 32 + c];
            __hip_bfloat162 v1 = xW2[(size_t)m1 * 32 + c];
            __hip_bfloat162 v2 = xW2[(size_t)m2 * 32 + c];
            __hip_bfloat162 v3 = xW2[(size_t)m3 * 32 + c];
            __hip_bfloat162 v4 = xW2[(size_t)m4 * 32 + c];
            __hip_bfloat162 v5 = xW2[(size_t)m5 * 32 + c];
            __hip_bfloat162 v6 = xW2[(size_t)m6 * 32 + c];
            __hip_bfloat162 v7 = xW2[(size_t)m7 * 32 + c];
            ax += __bfloat162float(v0.x); ay += __bfloat162float(v0.y);
            ax += __bfloat162float(v1.x); ay += __bfloat162float(v1.y);
            ax += __bfloat162float(v2.x); ay += __bfloat162float(v2.y);
            ax += __bfloat162float(v3.x); ay += __bfloat162float(v3.y);
            ax += __bfloat162float(v4.x); ay += __bfloat162float(v4.y);
            ax += __bfloat162float(v5.x); ay += __bfloat162float(v5.y);
            ax += __bfloat162float(v6.x); ay += __bfloat162float(v6.y);
            ax += __bfloat162float(v7.x); ay += __bfloat162float(v7.y);
        }
        for (; jj < nn; ++jj) {
            int m = __shfl(colv, jj, 32);
            __hip_bfloat162 v = xW2[(size_t)m * 32 + c];
            ax += __bfloat162float(v.x);
            ay += __bfloat162float(v.y);
        }
    }
    float di = dinv[wid];
    float2 b1v = ((const float2*)b1)[c];
    float h0 = fmaxf(fmaf(di, ax, b1v.x), 0.f);
    float h1 = fmaxf(fmaf(di, ay, b1v.y), 0.f);
    float4 Uv = ((const float4*)U)[c];   // {U[2c][0],U[2c][1],U[2c+1][0],U[2c+1][1]}
    float q0 = fmaf(h0, Uv.x, h1 * Uv.z);
    float q1 = fmaf(h0, Uv.y, h1 * Uv.w);
#pragma unroll
    for (int mm = 16; mm; mm >>= 1) {
        q0 += __shfl_xor(q0, mm);        // xor<32 stays within half-wave
        q1 += __shfl_xor(q1, mm);
    }
    if (c == 0) {
        Qs[2 * wid + 0] = di * q0;
        Qs[2 * wid + 1] = di * q1;
    }
}

// ---- conv2 scalar gather (Qs pre-scaled; self-term here) ----
__global__ void k_gather2(const float* __restrict__ dinv, const int* __restrict__ rp,
                          const int* __restrict__ col, const float* __restrict__ Qs,
                          float* __restrict__ P, int N) {
    int n = blockIdx.x * blockDim.x + threadIdx.x;
    if (n >= N) return;
    float2 self = ((const float2*)Qs)[n];
    float p0 = self.x, p1 = self.y;
    int beg = rp[n], end = rp[n + 1];
    int j = beg;
    for (; j + 4 <= end; j += 4) {
        int m0 = col[j + 0], m1 = col[j + 1], m2 = col[j + 2], m3 = col[j + 3];
        float2 q0 = ((const float2*)Qs)[m0];
        float2 q1 = ((const float2*)Qs)[m1];
        float2 q2 = ((const float2*)Qs)[m2];
        float2 q3 = ((const float2*)Qs)[m3];
        p0 += (q0.x + q1.x) + (q2.x + q3.x);
        p1 += (q0.y + q1.y) + (q2.y + q3.y);
    }
    for (; j < end; ++j) {
        float2 q = ((const float2*)Qs)[col[j]];
        p0 += q.x;
        p1 += q.y;
    }
    float di = dinv[n];
    P[2 * n + 0] = di * p0;
    P[2 * n + 1] = di * p1;
}

// ---------------- per-edge epilogue -> fp32 out ----------------
__global__ void k_edge(const int* __restrict__ src, const int* __restrict__ dst,
                       const int* __restrict__ attr, const float* __restrict__ P,
                       const float* __restrict__ E0t, const float* __restrict__ E1t,
                       const float* __restrict__ C, float* __restrict__ out, int E) {
    int e = blockIdx.x * blockDim.x + threadIdx.x;
    if (e >= E) return;
    int s = src[e], d = dst[e];
    float a0 = (float)attr[e];
    float a1 = (float)attr[E + e];
    int i2 = attr[2 * E + e], i3 = attr[3 * E + e];
    const float2* P2 = (const float2*)P;
    float2 ps = P2[s], pd = P2[d];
    float z0 = ps.x - pd.x + a0 * C[2] + a1 * C[4] + E0t[i2 * 2 + 0] + E1t[i3 * 2 + 0] + C[0];
    float z1 = ps.y - pd.y + a0 * C[3] + a1 * C[5] + E0t[i2 * 2 + 1] + E1t[i3 * 2 + 1] + C[1];
    float r0 = fmaxf(z0, 0.f), r1 = fmaxf(z1, 0.f);
    float o0 = r0 * C[6] + r1 * C[8] + C[10];
    float o1 = r0 * C[7] + r1 * C[9] + C[11];
    float m = fmaxf(o0, o1);
    float lse = m + logf(expf(o0 - m) + expf(o1 - m));
    float2 res;
    res.x = o0 - lse;
    res.y = o1 - lse;
    ((float2*)out)[e] = res;
}

extern "C" void kernel_launch(void* const* d_in, const int* in_sizes, int n_in,
                              void* d_out, int out_size, void* d_ws, size_t ws_size,
                              hipStream_t stream) {
    const float* x    = (const float*)d_in[0];
    const int*   ei   = (const int*)d_in[1];
    const int*   ea   = (const int*)d_in[2];
    const float* W1   = (const float*)d_in[3];
    const float* b1   = (const float*)d_in[4];
    const float* W2   = (const float*)d_in[5];
    const float* emb0 = (const float*)d_in[7];
    const float* emb1 = (const float*)d_in[8];
    const float* fcW1 = (const float*)d_in[9];
    const float* fcb1 = (const float*)d_in[10];
    const float* fcW2 = (const float*)d_in[11];
    const float* fcb2 = (const float*)d_in[12];

    int N = in_sizes[0] / 64;
    int E = in_sizes[1] / 2;
    const int* src = ei;
    const int* dst = ei + E;
    int NB = (N + 255) >> 8;                      // buckets of 256 nodes (391)
    int chunk = (E + NBLK - 1) / NBLK;

    // ws layout (4-byte words), ~15.6 MB (identical to R11):
    char* wsb = (char*)d_ws;
    float* dinv = (float*)wsb;                             // N
    int*   rp   = (int*)(wsb + (size_t)4 * 100352);        // N+1
    int*   cntm = (int*)(wsb + (size_t)4 * 200704);        // NB*NBLK
    int*   part = (int*)(wsb + (size_t)4 * 300800);        // 512
    float* U    = (float*)(wsb + (size_t)4 * 301312);      // 128
    float* E0t  = U + 128;                                 // 40
    float* E1t  = E0t + 40;                                // 40
    float* C    = E1t + 40;                                // 12  (ends 301532)
    int*   flags = (int*)(wsb + (size_t)4 * 301536);       // 8 ints (gap before Qs)
    float* Qs   = (float*)(wsb + (size_t)4 * 301568);      // 2N
    float* P    = (float*)(wsb + (size_t)4 * 501760);      // 2N
    bf16*  xWs  = (bf16*)(wsb + (size_t)4 * 702464);       // N*64 bf16 (12.8 MB)
    int*   col   = (int*)d_out;                            // E ints (first half)
    int*   pairs = (int*)d_out + E;                        // E ints (second half)
    // col+pairs = 2E ints = exactly out_size floats; k_edge overwrites last.

    hipMemsetAsync(flags, 0, 32, stream);
    k_build<<<NBLK, 256, 0, stream>>>(
        src, dst, x, W1, W2, emb0, emb1, fcW1, fcb1, fcW2, fcb2,
        cntm, part, U, E0t, E1t, C, pairs, col, rp, dinv, xWs, flags,
        N, E, NB, chunk);
    k_gather1<<<(N + 7) / 8, 256, 0, stream>>>(xWs, dinv, rp, col, b1, U, Qs, N, E);
    k_gather2<<<(N + 255) / 256, 256, 0, stream>>>(dinv, rp, col, Qs, P, N);
    k_edge<<<(E + 255) / 256, 256, 0, stream>>>(src, dst, ea, P, E0t, E1t, C,
                                                (float*)d_out, E);
}

// Round 5
// 285.273 us; speedup vs baseline: 1.9826x; 1.9826x over previous
//
#include <hip/hip_runtime.h>
#include <hip/hip_bf16.h>
#include <math.h>

// ---------------------------------------------------------------------------
// GCNWithEdge, algebraically folded + bucketed CSR gather. FP32 in/out.
//   xWs[n]   = dinv[n] * (x @ W1)[n]          (bf16, dinv folded in)
//   h1[n]    = relu(dinv[n]*(sum_{s->n} xWs[s] + xWs[n]) + b1)
//   Qs[n][c] = dinv[n] * (h1[n] . U[:,c]),  U = W2 @ fcW1[0:64,:]
//   P[n][c]  = dinv[n] * (sum_{s->n} Qs[s][c] + Qs[n][c])
//   z[e][c]  = P[s]-P[d] + a0*fcW1[64,c] + a1*fcW1[65,c] + E0t[a2]+E1t[a3]+fcb1
//   out = log_softmax( relu(z) @ fcW2 + fcb2 )
// R16: sync-free dispatch-count reduction (9 -> 7). R14 (cooperative) broke
// graph capture; R15 (atomic spin barrier) cost ~80us/barrier (poll storm on
// one line across 8 XCDs). So: only merges that need NO grid sync.
//   1. scan2small dispatch removed: kB re-derives the 391-entry part-scan
//      redundantly per block in LDS (~1-2us, proven scan code); block 0
//      publishes scanned bases to partS for kC. Tiny tables (U/E0t/E1t/C)
//      moved to idle kA blocks 192-194 (consumed >=2 dispatches later).
//   2. kC + gemm1 merged: gemm tile t covers nodes [64t,64t+64) inside
//      bucket t/4, and kC computes dinv for exactly its bucket -> one
//      391-block kernel does bucket finalize then its 4 gemm tiles with
//      only __syncthreads between phases. LDS union 33.3KB.
// kA/mscan1/gather1/gather2(1-thread/node)/edge = R11 verbatim (254us).
// ---------------------------------------------------------------------------

typedef __hip_bfloat16 bf16;
#define NBLK 256          // blocks for kA/kB; also the scan chunk size

// ---- kA: per-(bucket,block) histogram + folded tiny tables ----
__global__ __launch_bounds__(256) void kA(const int* __restrict__ dst,
                                          const float* __restrict__ W2,
                                          const float* __restrict__ emb0,
                                          const float* __restrict__ emb1,
                                          const float* __restrict__ fcW1,
                                          const float* __restrict__ fcb1,
                                          const float* __restrict__ fcW2,
                                          const float* __restrict__ fcb2,
                                          int* __restrict__ cntm,
                                          float* __restrict__ U,
                                          float* __restrict__ E0t,
                                          float* __restrict__ E1t,
                                          float* __restrict__ C,
                                          int E, int chunk, int NB) {
    __shared__ int h[512];
    int blk = blockIdx.x;
    int t = threadIdx.x;
    for (int i = t; i < NB; i += 256) h[i] = 0;
    __syncthreads();
    int lo = blk * chunk, hi = min(E, lo + chunk);
    for (int e = lo + t; e < hi; e += 256)
        atomicAdd(&h[dst[e] >> 8], 1);
    __syncthreads();
    for (int i = t; i < NB; i += 256)
        cntm[(size_t)i * NBLK + blk] = h[i];
    // tables on otherwise-idle tail work of 3 blocks (outputs consumed only
    // by gather1/edge, >=2 dispatch boundaries later)
    if (blk == 192) {
        if (t < 128) {
            int i = t >> 1, c = t & 1;
            float sum = 0.f;
            for (int j = 0; j < 64; ++j) sum += W2[i * 64 + j] * fcW1[j * 2 + c];
            U[i * 2 + c] = sum;                   // U = W2 @ fcW1[0:64,:]
        }
    } else if (blk == 193) {
        if (t < 40) {
            int i = t >> 1, c = t & 1;
            float s0 = 0.f, s1 = 0.f;
            for (int k = 0; k < 32; ++k) {
                s0 += emb0[i * 32 + k] * fcW1[(66 + k) * 2 + c];
                s1 += emb1[i * 32 + k] * fcW1[(98 + k) * 2 + c];
            }
            E0t[i * 2 + c] = s0;
            E1t[i * 2 + c] = s1;
        }
    } else if (blk == 194) {
        if (t == 0) {                             // b2 cancels in h2[s]-h2[d]
            C[0] = fcb1[0];  C[1] = fcb1[1];
            C[2] = fcW1[128]; C[3] = fcW1[129];
            C[4] = fcW1[130]; C[5] = fcW1[131];
            C[6] = fcW2[0];  C[7] = fcW2[1];
            C[8] = fcW2[2];  C[9] = fcW2[3];
            C[10] = fcb2[0]; C[11] = fcb2[1];
        }
    }
}

// ---- local exclusive scan of cntm chunks; part[r] = row total ----
__global__ void k_mscan1(int* __restrict__ a, int* __restrict__ part, int M) {
    __shared__ int s[256];
    int i = blockIdx.x * 256 + threadIdx.x;
    int v = (i < M) ? a[i] : 0;
    s[threadIdx.x] = v;
    int x = v;
    for (int off = 1; off < 256; off <<= 1) {
        __syncthreads();
        int add = (threadIdx.x >= off) ? s[threadIdx.x - off] : 0;
        __syncthreads();
        x += add;
        s[threadIdx.x] = x;
    }
    if (i < M) a[i] = x - v;
    __syncthreads();
    if (threadIdx.x == 255) part[blockIdx.x] = s[255];
}

// ---- kB: per-block redundant part-scan, then place packed pairs ----
__global__ __launch_bounds__(256) void kB(const int* __restrict__ src,
                                          const int* __restrict__ dst,
                                          const int* __restrict__ cntm,
                                          const int* __restrict__ part,
                                          int* __restrict__ partS,
                                          int* __restrict__ pairs,
                                          int E, int chunk, int NB) {
    __shared__ int sc[256];
    __shared__ int base[512];
    int blk = blockIdx.x;
    int t = threadIdx.x;
    // exclusive scan of part[0..NB) (NB <= 512), two 256-chunks (proven code)
    int v2 = (256 + t < NB) ? part[256 + t] : 0;
    int v1 = (t < NB) ? part[t] : 0;
    sc[t] = v1;
    int x1 = v1;
    for (int off = 1; off < 256; off <<= 1) {
        __syncthreads();
        int add = (t >= off) ? sc[t - off] : 0;
        __syncthreads();
        x1 += add;
        sc[t] = x1;
    }
    __syncthreads();
    int tot1 = sc[255];
    base[t] = x1 - v1;
    __syncthreads();
    sc[t] = v2;
    int x2 = v2;
    for (int off = 1; off < 256; off <<= 1) {
        __syncthreads();
        int add = (t >= off) ? sc[t - off] : 0;
        __syncthreads();
        x2 += add;
        sc[t] = x2;
    }
    base[256 + t] = tot1 + (x2 - v2);
    __syncthreads();
    if (blk == 0) {                               // publish bucket bases for kCG
        if (t < NB) partS[t] = base[t];
        if (256 + t < NB) partS[256 + t] = base[256 + t];
    }
    for (int i = t; i < NB; i += 256)             // cursors: base + local offset
        base[i] += cntm[(size_t)i * NBLK + blk];
    __syncthreads();
    int lo = blk * chunk, hi = min(E, lo + chunk);
    for (int e = lo + t; e < hi; e += 256) {
        int d = dst[e];
        int pos = atomicAdd(&base[d >> 8], 1);
        pairs[pos] = ((d & 255) << 17) | src[e];
    }
}

// ---- kCG: per-bucket CSR finalize (kC) + this bucket's 4 gemm tiles ----
__global__ __launch_bounds__(256) void kCG(const int* __restrict__ partS,
                                           const int* __restrict__ pairs,
                                           const float* __restrict__ x,
                                           const float* __restrict__ W1,
                                           int* __restrict__ col, int* __restrict__ rp,
                                           float* __restrict__ dinv,
                                           bf16* __restrict__ xWs,
                                           int N, int E, int NB) {
    __shared__ __align__(16) union {
        struct { int cnt[256]; int s[256]; } c;        // kC phase
        struct { float xs[64][66]; float Ws[64][64]; } g;  // gemm phase
    } sh;
    int b = blockIdx.x, t = threadIdx.x;
    int n0 = b << 8;
    int nn = min(256, N - n0);
    int base = partS[b];
    int end  = (b == NB - 1) ? E : partS[b + 1];
    sh.c.cnt[t] = 0;
    __syncthreads();
    for (int j = base + t; j < end; j += 256)
        atomicAdd(&sh.c.cnt[pairs[j] >> 17], 1);
    __syncthreads();
    int v = sh.c.cnt[t];
    if (t < nn) dinv[n0 + t] = rsqrtf((float)v + 1.0f);   // +1 self-loop
    sh.c.s[t] = v;
    int xx = v;
    for (int off = 1; off < 256; off <<= 1) {
        __syncthreads();
        int add = (t >= off) ? sh.c.s[t - off] : 0;
        __syncthreads();
        xx += add;
        sh.c.s[t] = xx;
    }
    __syncthreads();
    int excl = xx - v;
    if (t < nn) rp[n0 + t] = base + excl;
    sh.c.cnt[t] = base + excl;                            // cursor
    __syncthreads();
    for (int j = base + t; j < end; j += 256) {
        int v2 = pairs[j];
        int pos = atomicAdd(&sh.c.cnt[v2 >> 17], 1);
        col[pos] = v2 & 0x1FFFF;
    }
    if (b == NB - 1 && t == 0) rp[N] = E;

    // ---- gemm tiles of this bucket: xWs = dinv * (x @ W1), 4x4 blocking ----
    int tr = t >> 4;
    int tc = t & 15;
    for (int tile = 0; tile < 4; ++tile) {
        int ng = n0 + (tile << 6);
        if (ng >= N) break;
        __syncthreads();                                   // protect LDS reuse
        for (int i = t; i < 4096; i += 256) sh.g.Ws[i >> 6][i & 63] = W1[i];
        for (int i = t; i < 4096; i += 256) {
            int node = i >> 6, k = i & 63;
            float vv = (ng + node < N) ? x[(size_t)(ng + node) * 64 + k] : 0.f;
            sh.g.xs[k][node] = vv;
        }
        __syncthreads();
        float acc[4][4] = {};
#pragma unroll 8
        for (int k = 0; k < 64; ++k) {
            float2 xa = *(const float2*)&sh.g.xs[k][tr * 4];
            float2 xb = *(const float2*)&sh.g.xs[k][tr * 4 + 2];
            float4 wv = *(const float4*)&sh.g.Ws[k][tc * 4];
            acc[0][0] = fmaf(xa.x, wv.x, acc[0][0]);
            acc[0][1] = fmaf(xa.x, wv.y, acc[0][1]);
            acc[0][2] = fmaf(xa.x, wv.z, acc[0][2]);
            acc[0][3] = fmaf(xa.x, wv.w, acc[0][3]);
            acc[1][0] = fmaf(xa.y, wv.x, acc[1][0]);
            acc[1][1] = fmaf(xa.y, wv.y, acc[1][1]);
            acc[1][2] = fmaf(xa.y, wv.z, acc[1][2]);
            acc[1][3] = fmaf(xa.y, wv.w, acc[1][3]);
            acc[2][0] = fmaf(xb.x, wv.x, acc[2][0]);
            acc[2][1] = fmaf(xb.x, wv.y, acc[2][1]);
            acc[2][2] = fmaf(xb.x, wv.z, acc[2][2]);
            acc[2][3] = fmaf(xb.x, wv.w, acc[2][3]);
            acc[3][0] = fmaf(xb.y, wv.x, acc[3][0]);
            acc[3][1] = fmaf(xb.y, wv.y, acc[3][1]);
            acc[3][2] = fmaf(xb.y, wv.z, acc[3][2]);
            acc[3][3] = fmaf(xb.y, wv.w, acc[3][3]);
        }
#pragma unroll
        for (int i = 0; i < 4; ++i) {
            int node = ng + tr * 4 + i;
            if (node < N) {
                float di = dinv[node];
                __hip_bfloat162 p0, p1;
                p0.x = __float2bfloat16(di * acc[i][0]);
                p0.y = __float2bfloat16(di * acc[i][1]);
                p1.x = __float2bfloat16(di * acc[i][2]);
                p1.y = __float2bfloat16(di * acc[i][3]);
                __hip_bfloat162* dst2 = (__hip_bfloat162*)&xWs[(size_t)node * 64 + tc * 4];
                dst2[0] = p0;
                dst2[1] = p1;
            }
        }
    }
}

// ---- conv1 gather: 32 lanes/node, bf16x2/lane, 2 nodes per wave ----
__global__ __launch_bounds__(256) void k_gather1(
        const bf16* __restrict__ xWs, const float* __restrict__ dinv,
        const int* __restrict__ rp, const int* __restrict__ col,
        const float* __restrict__ b1, const float* __restrict__ U,
        float* __restrict__ Qs, int N, int E) {
    int wid = blockIdx.x * 8 + (threadIdx.x >> 5);   // node id (8 per block)
    int c = threadIdx.x & 31;                        // channel pair: 2c, 2c+1
    if (wid >= N) return;
    const __hip_bfloat162* xW2 = (const __hip_bfloat162*)xWs;  // [n*32 + c]
    __hip_bfloat162 sv = xW2[(size_t)wid * 32 + c];
    float ax = __bfloat162float(sv.x);
    float ay = __bfloat162float(sv.y);
    int beg = rp[wid], end = rp[wid + 1];
    for (int base = beg; base < end; base += 32) {
        int nn = min(32, end - base);
        int colv = col[min(base + c, E - 1)];
        int jj = 0;
        for (; jj + 8 <= nn; jj += 8) {
            int m0 = __shfl(colv, jj + 0, 32);
            int m1 = __shfl(colv, jj + 1, 32);
            int m2 = __shfl(colv, jj + 2, 32);
            int m3 = __shfl(colv, jj + 3, 32);
            int m4 = __shfl(colv, jj + 4, 32);
            int m5 = __shfl(colv, jj + 5, 32);
            int m6 = __shfl(colv, jj + 6, 32);
            int m7 = __shfl(colv, jj + 7, 32);
            __hip_bfloat162 v0 = xW2[(size_t)m0 * 32 + c];
            __hip_bfloat162 v1 = xW2[(size_t)m1 * 32 + c];
            __hip_bfloat162 v2 = xW2[(size_t)m2 * 32 + c];
            __hip_bfloat162 v3 = xW2[(size_t)m3 * 32 + c];
            __hip_bfloat162 v4 = xW2[(size_t)m4 * 32 + c];
            __hip_bfloat162 v5 = xW2[(size_t)m5 * 32 + c];
            __hip_bfloat162 v6 = xW2[(size_t)m6 * 32 + c];
            __hip_bfloat162 v7 = xW2[(size_t)m7 * 32 + c];
            ax += __bfloat162float(v0.x); ay += __bfloat162float(v0.y);
            ax += __bfloat162float(v1.x); ay += __bfloat162float(v1.y);
            ax += __bfloat162float(v2.x); ay += __bfloat162float(v2.y);
            ax += __bfloat162float(v3.x); ay += __bfloat162float(v3.y);
            ax += __bfloat162float(v4.x); ay += __bfloat162float(v4.y);
            ax += __bfloat162float(v5.x); ay += __bfloat162float(v5.y);
            ax += __bfloat162float(v6.x); ay += __bfloat162float(v6.y);
            ax += __bfloat162float(v7.x); ay += __bfloat162float(v7.y);
        }
        for (; jj < nn; ++jj) {
            int m = __shfl(colv, jj, 32);
            __hip_bfloat162 v = xW2[(size_t)m * 32 + c];
            ax += __bfloat162float(v.x);
            ay += __bfloat162float(v.y);
        }
    }
    float di = dinv[wid];
    float2 b1v = ((const float2*)b1)[c];
    float h0 = fmaxf(fmaf(di, ax, b1v.x), 0.f);
    float h1 = fmaxf(fmaf(di, ay, b1v.y), 0.f);
    float4 Uv = ((const float4*)U)[c];   // {U[2c][0],U[2c][1],U[2c+1][0],U[2c+1][1]}
    float q0 = fmaf(h0, Uv.x, h1 * Uv.z);
    float q1 = fmaf(h0, Uv.y, h1 * Uv.w);
#pragma unroll
    for (int mm = 16; mm; mm >>= 1) {
        q0 += __shfl_xor(q0, mm);        // xor<32 stays within half-wave
        q1 += __shfl_xor(q1, mm);
    }
    if (c == 0) {
        Qs[2 * wid + 0] = di * q0;
        Qs[2 * wid + 1] = di * q1;
    }
}

// ---- conv2 scalar gather (Qs pre-scaled; self-term here) ----
__global__ void k_gather2(const float* __restrict__ dinv, const int* __restrict__ rp,
                          const int* __restrict__ col, const float* __restrict__ Qs,
                          float* __restrict__ P, int N) {
    int n = blockIdx.x * blockDim.x + threadIdx.x;
    if (n >= N) return;
    float2 self = ((const float2*)Qs)[n];
    float p0 = self.x, p1 = self.y;
    int beg = rp[n], end = rp[n + 1];
    int j = beg;
    for (; j + 4 <= end; j += 4) {
        int m0 = col[j + 0], m1 = col[j + 1], m2 = col[j + 2], m3 = col[j + 3];
        float2 q0 = ((const float2*)Qs)[m0];
        float2 q1 = ((const float2*)Qs)[m1];
        float2 q2 = ((const float2*)Qs)[m2];
        float2 q3 = ((const float2*)Qs)[m3];
        p0 += (q0.x + q1.x) + (q2.x + q3.x);
        p1 += (q0.y + q1.y) + (q2.y + q3.y);
    }
    for (; j < end; ++j) {
        float2 q = ((const float2*)Qs)[col[j]];
        p0 += q.x;
        p1 += q.y;
    }
    float di = dinv[n];
    P[2 * n + 0] = di * p0;
    P[2 * n + 1] = di * p1;
}

// ---------------- per-edge epilogue -> fp32 out ----------------
__global__ void k_edge(const int* __restrict__ src, const int* __restrict__ dst,
                       const int* __restrict__ attr, const float* __restrict__ P,
                       const float* __restrict__ E0t, const float* __restrict__ E1t,
                       const float* __restrict__ C, float* __restrict__ out, int E) {
    int e = blockIdx.x * blockDim.x + threadIdx.x;
    if (e >= E) return;
    int s = src[e], d = dst[e];
    float a0 = (float)attr[e];
    float a1 = (float)attr[E + e];
    int i2 = attr[2 * E + e], i3 = attr[3 * E + e];
    const float2* P2 = (const float2*)P;
    float2 ps = P2[s], pd = P2[d];
    float z0 = ps.x - pd.x + a0 * C[2] + a1 * C[4] + E0t[i2 * 2 + 0] + E1t[i3 * 2 + 0] + C[0];
    float z1 = ps.y - pd.y + a0 * C[3] + a1 * C[5] + E0t[i2 * 2 + 1] + E1t[i3 * 2 + 1] + C[1];
    float r0 = fmaxf(z0, 0.f), r1 = fmaxf(z1, 0.f);
    float o0 = r0 * C[6] + r1 * C[8] + C[10];
    float o1 = r0 * C[7] + r1 * C[9] + C[11];
    float m = fmaxf(o0, o1);
    float lse = m + logf(expf(o0 - m) + expf(o1 - m));
    float2 res;
    res.x = o0 - lse;
    res.y = o1 - lse;
    ((float2*)out)[e] = res;
}

extern "C" void kernel_launch(void* const* d_in, const int* in_sizes, int n_in,
                              void* d_out, int out_size, void* d_ws, size_t ws_size,
                              hipStream_t stream) {
    const float* x    = (const float*)d_in[0];
    const int*   ei   = (const int*)d_in[1];
    const int*   ea   = (const int*)d_in[2];
    const float* W1   = (const float*)d_in[3];
    const float* b1   = (const float*)d_in[4];
    const float* W2   = (const float*)d_in[5];
    const float* emb0 = (const float*)d_in[7];
    const float* emb1 = (const float*)d_in[8];
    const float* fcW1 = (const float*)d_in[9];
    const float* fcb1 = (const float*)d_in[10];
    const float* fcW2 = (const float*)d_in[11];
    const float* fcb2 = (const float*)d_in[12];

    const int N = in_sizes[0] / 64;
    const int E = in_sizes[1] / 2;
    const int* src = ei;
    const int* dst = ei + E;
    const int NB = (N + 255) >> 8;                // buckets of 256 nodes (391)
    const int NBB = NB * NBLK;                    // count-matrix size (~100K)
    const int chunk = (E + NBLK - 1) / NBLK;
    const int BS = (NBB + 255) / 256;             // scan chunks == NB (<=512)

    // ws layout (4-byte words), ~15.6 MB:
    char* wsb = (char*)d_ws;
    float* dinv = (float*)wsb;                             // N
    int*   rp   = (int*)(wsb + (size_t)4 * 100352);        // N+1
    int*   cntm = (int*)(wsb + (size_t)4 * 200704);        // NBB
    int*   part = (int*)(wsb + (size_t)4 * 300800);        // 512 (raw row totals)
    float* U    = (float*)(wsb + (size_t)4 * 301312);      // 128
    float* E0t  = U + 128;                                 // 40
    float* E1t  = E0t + 40;                                // 40
    float* C    = E1t + 40;                                // 12
    float* Qs   = (float*)(wsb + (size_t)4 * 301568);      // 2N
    float* P    = (float*)(wsb + (size_t)4 * 501760);      // 2N
    bf16*  xWs  = (bf16*)(wsb + (size_t)4 * 702464);       // N*64 bf16 (12.8 MB)
    int*   partS = (int*)(wsb + (size_t)4 * 3902464);      // 512 (scanned bases)
    int*   col   = (int*)d_out;                            // E ints (first half)
    int*   pairs = (int*)d_out + E;                        // E ints (second half)
    // col+pairs = 2E ints = exactly out_size floats; k_edge overwrites last.

    kA<<<NBLK, 256, 0, stream>>>(dst, W2, emb0, emb1, fcW1, fcb1, fcW2, fcb2,
                                 cntm, U, E0t, E1t, C, E, chunk, NB);
    k_mscan1<<<BS, 256, 0, stream>>>(cntm, part, NBB);
    kB<<<NBLK, 256, 0, stream>>>(src, dst, cntm, part, partS, pairs, E, chunk, NB);
    kCG<<<NB, 256, 0, stream>>>(partS, pairs, x, W1, col, rp, dinv, xWs, N, E, NB);
    k_gather1<<<(N + 7) / 8, 256, 0, stream>>>(xWs, dinv, rp, col, b1, U, Qs, N, E);
    k_gather2<<<(N + 255) / 256, 256, 0, stream>>>(dinv, rp, col, Qs, P, N);
    k_edge<<<(E + 255) / 256, 256, 0, stream>>>(src, dst, ea, P, E0t, E1t, C,
                                                (float*)d_out, E);
}

// Round 6
// 264.558 us; speedup vs baseline: 2.1379x; 1.0783x over previous
//
#include <hip/hip_runtime.h>
#include <hip/hip_bf16.h>
#include <math.h>

// ---------------------------------------------------------------------------
// GCNWithEdge, algebraically folded + bucketed CSR gather. FP32 in/out.
//   xWs[n]   = dinv[n] * (x @ W1)[n]          (bf16, dinv folded in)
//   h1[n]    = relu(dinv[n]*(sum_{s->n} xWs[s] + xWs[n]) + b1)
//   Qs[n][c] = dinv[n] * (h1[n] . U[:,c]),  U = W2 @ fcW1[0:64,:]
//   P[n][c]  = dinv[n] * (sum_{s->n} Qs[s][c] + Qs[n][c])
//   z[e][c]  = P[s]-P[d] + a0*fcW1[64,c] + a1*fcW1[65,c] + E0t[a2]+E1t[a3]+fcb1
//   out = log_softmax( relu(z) @ fcW2 + fcb2 )
// R17: keep R16's good half, revert its bad half. R16's kCG merge cost +47us
// (391 blocks serialize bucket-finalize + 4 gemm tiles; gemm lost its 1563-
// block parallelism). But R16's scan2small elimination is proven: kA carries
// the tiny tables on idle blocks 192-194; kB redundantly re-derives the
// 391-entry part-scan in LDS (~1-2us parallel) and block 0 publishes partS
// for kC. So R17 = R11's exact 9-kernel set minus the scan2small dispatch:
// kA(+tables), mscan1, kB(+partS), kC, gemm1, gather1, gather2, edge = 8.
// All hot kernel bodies byte-identical to R11 (254us). Isolates ONE variable:
// one dispatch boundary (~12-15us if the bubble audit is right).
// ---------------------------------------------------------------------------

typedef __hip_bfloat16 bf16;
#define NBLK 256          // blocks for kA/kB; also the scan chunk size

// ---- kA: per-(bucket,block) histogram + folded tiny tables ----
__global__ __launch_bounds__(256) void kA(const int* __restrict__ dst,
                                          const float* __restrict__ W2,
                                          const float* __restrict__ emb0,
                                          const float* __restrict__ emb1,
                                          const float* __restrict__ fcW1,
                                          const float* __restrict__ fcb1,
                                          const float* __restrict__ fcW2,
                                          const float* __restrict__ fcb2,
                                          int* __restrict__ cntm,
                                          float* __restrict__ U,
                                          float* __restrict__ E0t,
                                          float* __restrict__ E1t,
                                          float* __restrict__ C,
                                          int E, int chunk, int NB) {
    __shared__ int h[512];
    int blk = blockIdx.x;
    int t = threadIdx.x;
    for (int i = t; i < NB; i += 256) h[i] = 0;
    __syncthreads();
    int lo = blk * chunk, hi = min(E, lo + chunk);
    for (int e = lo + t; e < hi; e += 256)
        atomicAdd(&h[dst[e] >> 8], 1);
    __syncthreads();
    for (int i = t; i < NB; i += 256)
        cntm[(size_t)i * NBLK + blk] = h[i];
    // tables on otherwise-idle tail work of 3 blocks (outputs consumed only
    // by gather1/edge, >=2 dispatch boundaries later)
    if (blk == 192) {
        if (t < 128) {
            int i = t >> 1, c = t & 1;
            float sum = 0.f;
            for (int j = 0; j < 64; ++j) sum += W2[i * 64 + j] * fcW1[j * 2 + c];
            U[i * 2 + c] = sum;                   // U = W2 @ fcW1[0:64,:]
        }
    } else if (blk == 193) {
        if (t < 40) {
            int i = t >> 1, c = t & 1;
            float s0 = 0.f, s1 = 0.f;
            for (int k = 0; k < 32; ++k) {
                s0 += emb0[i * 32 + k] * fcW1[(66 + k) * 2 + c];
                s1 += emb1[i * 32 + k] * fcW1[(98 + k) * 2 + c];
            }
            E0t[i * 2 + c] = s0;
            E1t[i * 2 + c] = s1;
        }
    } else if (blk == 194) {
        if (t == 0) {                             // b2 cancels in h2[s]-h2[d]
            C[0] = fcb1[0];  C[1] = fcb1[1];
            C[2] = fcW1[128]; C[3] = fcW1[129];
            C[4] = fcW1[130]; C[5] = fcW1[131];
            C[6] = fcW2[0];  C[7] = fcW2[1];
            C[8] = fcW2[2];  C[9] = fcW2[3];
            C[10] = fcb2[0]; C[11] = fcb2[1];
        }
    }
}

// ---- local exclusive scan of cntm chunks; part[r] = row total ----
__global__ void k_mscan1(int* __restrict__ a, int* __restrict__ part, int M) {
    __shared__ int s[256];
    int i = blockIdx.x * 256 + threadIdx.x;
    int v = (i < M) ? a[i] : 0;
    s[threadIdx.x] = v;
    int x = v;
    for (int off = 1; off < 256; off <<= 1) {
        __syncthreads();
        int add = (threadIdx.x >= off) ? s[threadIdx.x - off] : 0;
        __syncthreads();
        x += add;
        s[threadIdx.x] = x;
    }
    if (i < M) a[i] = x - v;
    __syncthreads();
    if (threadIdx.x == 255) part[blockIdx.x] = s[255];
}

// ---- kB: per-block redundant part-scan, then place packed pairs ----
__global__ __launch_bounds__(256) void kB(const int* __restrict__ src,
                                          const int* __restrict__ dst,
                                          const int* __restrict__ cntm,
                                          const int* __restrict__ part,
                                          int* __restrict__ partS,
                                          int* __restrict__ pairs,
                                          int E, int chunk, int NB) {
    __shared__ int sc[256];
    __shared__ int base[512];
    int blk = blockIdx.x;
    int t = threadIdx.x;
    // exclusive scan of part[0..NB) (NB <= 512), two 256-chunks (proven code)
    int v2 = (256 + t < NB) ? part[256 + t] : 0;
    int v1 = (t < NB) ? part[t] : 0;
    sc[t] = v1;
    int x1 = v1;
    for (int off = 1; off < 256; off <<= 1) {
        __syncthreads();
        int add = (t >= off) ? sc[t - off] : 0;
        __syncthreads();
        x1 += add;
        sc[t] = x1;
    }
    __syncthreads();
    int tot1 = sc[255];
    base[t] = x1 - v1;
    __syncthreads();
    sc[t] = v2;
    int x2 = v2;
    for (int off = 1; off < 256; off <<= 1) {
        __syncthreads();
        int add = (t >= off) ? sc[t - off] : 0;
        __syncthreads();
        x2 += add;
        sc[t] = x2;
    }
    base[256 + t] = tot1 + (x2 - v2);
    __syncthreads();
    if (blk == 0) {                               // publish bucket bases for kC
        if (t < NB) partS[t] = base[t];
        if (256 + t < NB) partS[256 + t] = base[256 + t];
    }
    for (int i = t; i < NB; i += 256)             // cursors: base + local offset
        base[i] += cntm[(size_t)i * NBLK + blk];
    __syncthreads();
    int lo = blk * chunk, hi = min(E, lo + chunk);
    for (int e = lo + t; e < hi; e += 256) {
        int d = dst[e];
        int pos = atomicAdd(&base[d >> 8], 1);
        pairs[pos] = ((d & 255) << 17) | src[e];
    }
}

// ---- kC: per-bucket CSR finalize: dinv, rp, col ----
__global__ __launch_bounds__(256) void kC(const int* __restrict__ partS,
                                          const int* __restrict__ pairs,
                                          int* __restrict__ col, int* __restrict__ rp,
                                          float* __restrict__ dinv,
                                          int N, int E, int NB) {
    __shared__ int cnt[256];
    __shared__ int s[256];
    int b = blockIdx.x, t = threadIdx.x;
    int n0 = b << 8;
    int nn = min(256, N - n0);
    int base = partS[b];
    int end  = (b == NB - 1) ? E : partS[b + 1];
    cnt[t] = 0;
    __syncthreads();
    for (int j = base + t; j < end; j += 256)
        atomicAdd(&cnt[pairs[j] >> 17], 1);
    __syncthreads();
    int v = cnt[t];
    if (t < nn) dinv[n0 + t] = rsqrtf((float)v + 1.0f);   // +1 self-loop
    s[t] = v;
    int x = v;
    for (int off = 1; off < 256; off <<= 1) {
        __syncthreads();
        int add = (t >= off) ? s[t - off] : 0;
        __syncthreads();
        x += add;
        s[t] = x;
    }
    __syncthreads();
    int excl = x - v;
    if (t < nn) rp[n0 + t] = base + excl;
    cnt[t] = base + excl;                                 // cursor
    __syncthreads();
    for (int j = base + t; j < end; j += 256) {
        int v2 = pairs[j];
        int pos = atomicAdd(&cnt[v2 >> 17], 1);
        col[pos] = v2 & 0x1FFFF;
    }
    if (b == NB - 1 && t == 0) rp[N] = E;
}

// ---------------- xWs = dinv * (x @ W1), LDS-tiled 4x4 blocking ----------------
__global__ __launch_bounds__(256) void k_gemm1(const float* __restrict__ x,
                                               const float* __restrict__ W1,
                                               const float* __restrict__ dinv,
                                               bf16* __restrict__ xWs, int N) {
    __shared__ __align__(16) float xs[64][66];   // pad 66: write stride 2 banks (free)
    __shared__ __align__(16) float Ws[64][64];
    int tid = threadIdx.x;
    int n0 = blockIdx.x * 64;
    for (int i = tid; i < 4096; i += 256) Ws[i >> 6][i & 63] = W1[i];
    for (int i = tid; i < 4096; i += 256) {
        int node = i >> 6, k = i & 63;
        float v = (n0 + node < N) ? x[(size_t)(n0 + node) * 64 + k] : 0.f;
        xs[k][node] = v;
    }
    __syncthreads();
    int tr = tid >> 4;
    int tc = tid & 15;
    float acc[4][4] = {};
#pragma unroll 8
    for (int k = 0; k < 64; ++k) {
        float2 xa = *(const float2*)&xs[k][tr * 4];
        float2 xb = *(const float2*)&xs[k][tr * 4 + 2];
        float4 wv = *(const float4*)&Ws[k][tc * 4];
        acc[0][0] = fmaf(xa.x, wv.x, acc[0][0]);
        acc[0][1] = fmaf(xa.x, wv.y, acc[0][1]);
        acc[0][2] = fmaf(xa.x, wv.z, acc[0][2]);
        acc[0][3] = fmaf(xa.x, wv.w, acc[0][3]);
        acc[1][0] = fmaf(xa.y, wv.x, acc[1][0]);
        acc[1][1] = fmaf(xa.y, wv.y, acc[1][1]);
        acc[1][2] = fmaf(xa.y, wv.z, acc[1][2]);
        acc[1][3] = fmaf(xa.y, wv.w, acc[1][3]);
        acc[2][0] = fmaf(xb.x, wv.x, acc[2][0]);
        acc[2][1] = fmaf(xb.x, wv.y, acc[2][1]);
        acc[2][2] = fmaf(xb.x, wv.z, acc[2][2]);
        acc[2][3] = fmaf(xb.x, wv.w, acc[2][3]);
        acc[3][0] = fmaf(xb.y, wv.x, acc[3][0]);
        acc[3][1] = fmaf(xb.y, wv.y, acc[3][1]);
        acc[3][2] = fmaf(xb.y, wv.z, acc[3][2]);
        acc[3][3] = fmaf(xb.y, wv.w, acc[3][3]);
    }
#pragma unroll
    for (int i = 0; i < 4; ++i) {
        int node = n0 + tr * 4 + i;
        if (node < N) {
            float di = dinv[node];
            __hip_bfloat162 p0, p1;
            p0.x = __float2bfloat16(di * acc[i][0]);
            p0.y = __float2bfloat16(di * acc[i][1]);
            p1.x = __float2bfloat16(di * acc[i][2]);
            p1.y = __float2bfloat16(di * acc[i][3]);
            __hip_bfloat162* dst2 = (__hip_bfloat162*)&xWs[(size_t)node * 64 + tc * 4];
            dst2[0] = p0;
            dst2[1] = p1;
        }
    }
}

// ---- conv1 gather: 32 lanes/node, bf16x2/lane, 2 nodes per wave ----
__global__ __launch_bounds__(256) void k_gather1(
        const bf16* __restrict__ xWs, const float* __restrict__ dinv,
        const int* __restrict__ rp, const int* __restrict__ col,
        const float* __restrict__ b1, const float* __restrict__ U,
        float* __restrict__ Qs, int N, int E) {
    int wid = blockIdx.x * 8 + (threadIdx.x >> 5);   // node id (8 per block)
    int c = threadIdx.x & 31;                        // channel pair: 2c, 2c+1
    if (wid >= N) return;
    const __hip_bfloat162* xW2 = (const __hip_bfloat162*)xWs;  // [n*32 + c]
    __hip_bfloat162 sv = xW2[(size_t)wid * 32 + c];
    float ax = __bfloat162float(sv.x);
    float ay = __bfloat162float(sv.y);
    int beg = rp[wid], end = rp[wid + 1];
    for (int base = beg; base < end; base += 32) {
        int nn = min(32, end - base);
        int colv = col[min(base + c, E - 1)];
        int jj = 0;
        for (; jj + 8 <= nn; jj += 8) {
            int m0 = __shfl(colv, jj + 0, 32);
            int m1 = __shfl(colv, jj + 1, 32);
            int m2 = __shfl(colv, jj + 2, 32);
            int m3 = __shfl(colv, jj + 3, 32);
            int m4 = __shfl(colv, jj + 4, 32);
            int m5 = __shfl(colv, jj + 5, 32);
            int m6 = __shfl(colv, jj + 6, 32);
            int m7 = __shfl(colv, jj + 7, 32);
            __hip_bfloat162 v0 = xW2[(size_t)m0 * 32 + c];
            __hip_bfloat162 v1 = xW2[(size_t)m1 * 32 + c];
            __hip_bfloat162 v2 = xW2[(size_t)m2 * 32 + c];
            __hip_bfloat162 v3 = xW2[(size_t)m3 * 32 + c];
            __hip_bfloat162 v4 = xW2[(size_t)m4 * 32 + c];
            __hip_bfloat162 v5 = xW2[(size_t)m5 * 32 + c];
            __hip_bfloat162 v6 = xW2[(size_t)m6 * 32 + c];
            __hip_bfloat162 v7 = xW2[(size_t)m7 * 32 + c];
            ax += __bfloat162float(v0.x); ay += __bfloat162float(v0.y);
            ax += __bfloat162float(v1.x); ay += __bfloat162float(v1.y);
            ax += __bfloat162float(v2.x); ay += __bfloat162float(v2.y);
            ax += __bfloat162float(v3.x); ay += __bfloat162float(v3.y);
            ax += __bfloat162float(v4.x); ay += __bfloat162float(v4.y);
            ax += __bfloat162float(v5.x); ay += __bfloat162float(v5.y);
            ax += __bfloat162float(v6.x); ay += __bfloat162float(v6.y);
            ax += __bfloat162float(v7.x); ay += __bfloat162float(v7.y);
        }
        for (; jj < nn; ++jj) {
            int m = __shfl(colv, jj, 32);
            __hip_bfloat162 v = xW2[(size_t)m * 32 + c];
            ax += __bfloat162float(v.x);
            ay += __bfloat162float(v.y);
        }
    }
    float di = dinv[wid];
    float2 b1v = ((const float2*)b1)[c];
    float h0 = fmaxf(fmaf(di, ax, b1v.x), 0.f);
    float h1 = fmaxf(fmaf(di, ay, b1v.y), 0.f);
    float4 Uv = ((const float4*)U)[c];   // {U[2c][0],U[2c][1],U[2c+1][0],U[2c+1][1]}
    float q0 = fmaf(h0, Uv.x, h1 * Uv.z);
    float q1 = fmaf(h0, Uv.y, h1 * Uv.w);
#pragma unroll
    for (int mm = 16; mm; mm >>= 1) {
        q0 += __shfl_xor(q0, mm);        // xor<32 stays within half-wave
        q1 += __shfl_xor(q1, mm);
    }
    if (c == 0) {
        Qs[2 * wid + 0] = di * q0;
        Qs[2 * wid + 1] = di * q1;
    }
}

// ---- conv2 scalar gather (Qs pre-scaled; self-term here) ----
__global__ void k_gather2(const float* __restrict__ dinv, const int* __restrict__ rp,
                          const int* __restrict__ col, const float* __restrict__ Qs,
                          float* __restrict__ P, int N) {
    int n = blockIdx.x * blockDim.x + threadIdx.x;
    if (n >= N) return;
    float2 self = ((const float2*)Qs)[n];
    float p0 = self.x, p1 = self.y;
    int beg = rp[n], end = rp[n + 1];
    int j = beg;
    for (; j + 4 <= end; j += 4) {
        int m0 = col[j + 0], m1 = col[j + 1], m2 = col[j + 2], m3 = col[j + 3];
        float2 q0 = ((const float2*)Qs)[m0];
        float2 q1 = ((const float2*)Qs)[m1];
        float2 q2 = ((const float2*)Qs)[m2];
        float2 q3 = ((const float2*)Qs)[m3];
        p0 += (q0.x + q1.x) + (q2.x + q3.x);
        p1 += (q0.y + q1.y) + (q2.y + q3.y);
    }
    for (; j < end; ++j) {
        float2 q = ((const float2*)Qs)[col[j]];
        p0 += q.x;
        p1 += q.y;
    }
    float di = dinv[n];
    P[2 * n + 0] = di * p0;
    P[2 * n + 1] = di * p1;
}

// ---------------- per-edge epilogue -> fp32 out ----------------
__global__ void k_edge(const int* __restrict__ src, const int* __restrict__ dst,
                       const int* __restrict__ attr, const float* __restrict__ P,
                       const float* __restrict__ E0t, const float* __restrict__ E1t,
                       const float* __restrict__ C, float* __restrict__ out, int E) {
    int e = blockIdx.x * blockDim.x + threadIdx.x;
    if (e >= E) return;
    int s = src[e], d = dst[e];
    float a0 = (float)attr[e];
    float a1 = (float)attr[E + e];
    int i2 = attr[2 * E + e], i3 = attr[3 * E + e];
    const float2* P2 = (const float2*)P;
    float2 ps = P2[s], pd = P2[d];
    float z0 = ps.x - pd.x + a0 * C[2] + a1 * C[4] + E0t[i2 * 2 + 0] + E1t[i3 * 2 + 0] + C[0];
    float z1 = ps.y - pd.y + a0 * C[3] + a1 * C[5] + E0t[i2 * 2 + 1] + E1t[i3 * 2 + 1] + C[1];
    float r0 = fmaxf(z0, 0.f), r1 = fmaxf(z1, 0.f);
    float o0 = r0 * C[6] + r1 * C[8] + C[10];
    float o1 = r0 * C[7] + r1 * C[9] + C[11];
    float m = fmaxf(o0, o1);
    float lse = m + logf(expf(o0 - m) + expf(o1 - m));
    float2 res;
    res.x = o0 - lse;
    res.y = o1 - lse;
    ((float2*)out)[e] = res;
}

extern "C" void kernel_launch(void* const* d_in, const int* in_sizes, int n_in,
                              void* d_out, int out_size, void* d_ws, size_t ws_size,
                              hipStream_t stream) {
    const float* x    = (const float*)d_in[0];
    const int*   ei   = (const int*)d_in[1];
    const int*   ea   = (const int*)d_in[2];
    const float* W1   = (const float*)d_in[3];
    const float* b1   = (const float*)d_in[4];
    const float* W2   = (const float*)d_in[5];
    const float* emb0 = (const float*)d_in[7];
    const float* emb1 = (const float*)d_in[8];
    const float* fcW1 = (const float*)d_in[9];
    const float* fcb1 = (const float*)d_in[10];
    const float* fcW2 = (const float*)d_in[11];
    const float* fcb2 = (const float*)d_in[12];

    const int N = in_sizes[0] / 64;
    const int E = in_sizes[1] / 2;
    const int* src = ei;
    const int* dst = ei + E;
    const int NB = (N + 255) >> 8;                // buckets of 256 nodes (391)
    const int NBB = NB * NBLK;                    // count-matrix size (~100K)
    const int chunk = (E + NBLK - 1) / NBLK;
    const int BS = (NBB + 255) / 256;             // scan chunks == NB (<=512)

    // ws layout (4-byte words), ~15.6 MB:
    char* wsb = (char*)d_ws;
    float* dinv = (float*)wsb;                             // N
    int*   rp   = (int*)(wsb + (size_t)4 * 100352);        // N+1
    int*   cntm = (int*)(wsb + (size_t)4 * 200704);        // NBB
    int*   part = (int*)(wsb + (size_t)4 * 300800);        // 512 (raw row totals)
    float* U    = (float*)(wsb + (size_t)4 * 301312);      // 128
    float* E0t  = U + 128;                                 // 40
    float* E1t  = E0t + 40;                                // 40
    float* C    = E1t + 40;                                // 12
    float* Qs   = (float*)(wsb + (size_t)4 * 301568);      // 2N
    float* P    = (float*)(wsb + (size_t)4 * 501760);      // 2N
    bf16*  xWs  = (bf16*)(wsb + (size_t)4 * 702464);       // N*64 bf16 (12.8 MB)
    int*   partS = (int*)(wsb + (size_t)4 * 3902464);      // 512 (scanned bases)
    int*   col   = (int*)d_out;                            // E ints (first half)
    int*   pairs = (int*)d_out + E;                        // E ints (second half)
    // col+pairs = 2E ints = exactly out_size floats; k_edge overwrites last.

    kA<<<NBLK, 256, 0, stream>>>(dst, W2, emb0, emb1, fcW1, fcb1, fcW2, fcb2,
                                 cntm, U, E0t, E1t, C, E, chunk, NB);
    k_mscan1<<<BS, 256, 0, stream>>>(cntm, part, NBB);
    kB<<<NBLK, 256, 0, stream>>>(src, dst, cntm, part, partS, pairs, E, chunk, NB);
    kC<<<NB, 256, 0, stream>>>(partS, pairs, col, rp, dinv, N, E, NB);
    k_gemm1<<<(N + 63) / 64, 256, 0, stream>>>(x, W1, dinv, xWs, N);
    k_gather1<<<(N + 7) / 8, 256, 0, stream>>>(xWs, dinv, rp, col, b1, U, Qs, N, E);
    k_gather2<<<(N + 255) / 256, 256, 0, stream>>>(dinv, rp, col, Qs, P, N);
    k_edge<<<(E + 255) / 256, 256, 0, stream>>>(src, dst, ea, P, E0t, E1t, C,
                                                (float*)d_out, E);
}

// Round 7
// 259.752 us; speedup vs baseline: 2.1774x; 1.0185x over previous
//
#include <hip/hip_runtime.h>
#include <hip/hip_bf16.h>
#include <math.h>

// ---------------------------------------------------------------------------
// GCNWithEdge, algebraically folded + bucketed CSR gather. FP32 in/out.
//   xWs[n]   = dinv[n] * (x @ W1)[n]          (bf16, dinv folded in)
//   h1[n]    = relu(dinv[n]*(sum_{s->n} xWs[s] + xWs[n]) + b1)
//   Qs[n][c] = dinv[n] * (h1[n] . U[:,c]),  U = W2 @ fcW1[0:64,:]
//   P[n][c]  = dinv[n] * (sum_{s->n} Qs[s][c] + Qs[n][c])
//   z[e][c]  = P[s]-P[d] + a0*fcW1[64,c] + a1*fcW1[65,c] + E0t[a2]+E1t[a3]+fcb1
//   out = log_softmax( relu(z) @ fcW2 + fcb2 )
// R18: exact restore of R11 (best measured: 253.2/254.5us). Session ledger:
// R12 global-atomic CSR -150us; R13 8-lane gather2 -19us; R14 cooperative
// fusion = capture crash; R15 spin-barrier fusion -310us (poll storm);
// R16 kC+gemm merge -31us (serialized gemm, occupancy loss); R17 dispatch
// count 9->8 = -10us/noise (launch-bubble theory falsified: boundary cost
// ~0-3us). Residual above ~100us of kernel time is harness re-poison fills
// (268MB @ 80% HBM, ~41us each) + graph-replay fixed cost — not reachable
// from kernel_launch. R11's structure is the verified optimum: LDS-cursor
// bucket radix CSR build, dinv-folded bf16 xWs, 32-lane/node gather1
// (mandatory 128B/edge: ReLU forces full 64-dim aggregation pre-projection),
// 2-dim Qs gather2, fully-folded per-edge epilogue.
// ---------------------------------------------------------------------------

typedef __hip_bfloat16 bf16;
#define NBLK 256          // blocks for kA/kB; also the scan chunk size

// ---- kA: per-(bucket,block) histogram ----
__global__ __launch_bounds__(256) void kA(const int* __restrict__ dst,
                                          int* __restrict__ cntm,
                                          int E, int chunk, int NB) {
    __shared__ int h[512];
    int blk = blockIdx.x;
    for (int i = threadIdx.x; i < NB; i += 256) h[i] = 0;
    __syncthreads();
    int lo = blk * chunk, hi = min(E, lo + chunk);
    for (int e = lo + threadIdx.x; e < hi; e += 256)
        atomicAdd(&h[dst[e] >> 8], 1);
    __syncthreads();
    for (int i = threadIdx.x; i < NB; i += 256)
        cntm[(size_t)i * NBLK + blk] = h[i];
}

// ---- local exclusive scan of cntm chunks (chunk = 256 = one bucket row) ----
__global__ void k_mscan1(int* __restrict__ a, int* __restrict__ part, int M) {
    __shared__ int s[256];
    int i = blockIdx.x * 256 + threadIdx.x;
    int v = (i < M) ? a[i] : 0;
    s[threadIdx.x] = v;
    int x = v;
    for (int off = 1; off < 256; off <<= 1) {
        __syncthreads();
        int add = (threadIdx.x >= off) ? s[threadIdx.x - off] : 0;
        __syncthreads();
        x += add;
        s[threadIdx.x] = x;
    }
    if (i < M) a[i] = x - v;
    __syncthreads();
    if (threadIdx.x == 255) part[blockIdx.x] = s[255];
}

// ---- single block: scan part (bucket bases) + all folded tiny tables ----
__global__ __launch_bounds__(512) void k_scan2small(
        int* __restrict__ part, int B,
        const float* __restrict__ W2,
        const float* __restrict__ emb0, const float* __restrict__ emb1,
        const float* __restrict__ fcW1, const float* __restrict__ fcb1,
        const float* __restrict__ fcW2, const float* __restrict__ fcb2,
        float* __restrict__ U, float* __restrict__ E0t,
        float* __restrict__ E1t, float* __restrict__ C) {
    __shared__ int s[512];
    int t = threadIdx.x;
    int v = (t < B) ? part[t] : 0;
    s[t] = v;
    int x = v;
    for (int off = 1; off < 512; off <<= 1) {
        __syncthreads();
        int add = (t >= off) ? s[t - off] : 0;
        __syncthreads();
        x += add;
        s[t] = x;
    }
    if (t < B) part[t] = x - v;
    // tables (independent of scan)
    if (t < 128) {
        int i = t >> 1, c = t & 1;
        float sum = 0.f;
        for (int j = 0; j < 64; ++j) sum += W2[i * 64 + j] * fcW1[j * 2 + c];
        U[i * 2 + c] = sum;                       // U = W2 @ fcW1[0:64,:]
    } else if (t < 168) {
        int i = (t - 128) >> 1, c = t & 1;
        float s0 = 0.f, s1 = 0.f;
        for (int k = 0; k < 32; ++k) {
            s0 += emb0[i * 32 + k] * fcW1[(66 + k) * 2 + c];
            s1 += emb1[i * 32 + k] * fcW1[(98 + k) * 2 + c];
        }
        E0t[i * 2 + c] = s0;
        E1t[i * 2 + c] = s1;
    } else if (t == 168) {                        // b2 cancels in h2[s]-h2[d]
        C[0] = fcb1[0];  C[1] = fcb1[1];
        C[2] = fcW1[128]; C[3] = fcW1[129];
        C[4] = fcW1[130]; C[5] = fcW1[131];
        C[6] = fcW2[0];  C[7] = fcW2[1];
        C[8] = fcW2[2];  C[9] = fcW2[3];
        C[10] = fcb2[0]; C[11] = fcb2[1];
    }
}

// ---- kB: place packed pairs; global offset = local-scan + part[bucket] ----
__global__ __launch_bounds__(256) void kB(const int* __restrict__ src,
                                          const int* __restrict__ dst,
                                          const int* __restrict__ cntm,
                                          const int* __restrict__ part,
                                          int* __restrict__ pairs,
                                          int E, int chunk, int NB) {
    __shared__ int off[512];
    int blk = blockIdx.x;
    for (int i = threadIdx.x; i < NB; i += 256)
        off[i] = cntm[(size_t)i * NBLK + blk] + part[i];
    __syncthreads();
    int lo = blk * chunk, hi = min(E, lo + chunk);
    for (int e = lo + threadIdx.x; e < hi; e += 256) {
        int d = dst[e];
        int pos = atomicAdd(&off[d >> 8], 1);
        pairs[pos] = ((d & 255) << 17) | src[e];
    }
}

// ---- kC: per-bucket CSR finalize: dinv, rp, col ----
__global__ __launch_bounds__(256) void kC(const int* __restrict__ part,
                                          const int* __restrict__ pairs,
                                          int* __restrict__ col, int* __restrict__ rp,
                                          float* __restrict__ dinv,
                                          int N, int E, int NB) {
    __shared__ int cnt[256];
    __shared__ int s[256];
    int b = blockIdx.x, t = threadIdx.x;
    int n0 = b << 8;
    int nn = min(256, N - n0);
    int base = part[b];
    int end  = (b == NB - 1) ? E : part[b + 1];
    cnt[t] = 0;
    __syncthreads();
    for (int j = base + t; j < end; j += 256)
        atomicAdd(&cnt[pairs[j] >> 17], 1);
    __syncthreads();
    int v = cnt[t];
    if (t < nn) dinv[n0 + t] = rsqrtf((float)v + 1.0f);   // +1 self-loop
    s[t] = v;
    int x = v;
    for (int off = 1; off < 256; off <<= 1) {
        __syncthreads();
        int add = (t >= off) ? s[t - off] : 0;
        __syncthreads();
        x += add;
        s[t] = x;
    }
    __syncthreads();
    int excl = x - v;
    if (t < nn) rp[n0 + t] = base + excl;
    cnt[t] = base + excl;                                 // cursor
    __syncthreads();
    for (int j = base + t; j < end; j += 256) {
        int v2 = pairs[j];
        int pos = atomicAdd(&cnt[v2 >> 17], 1);
        col[pos] = v2 & 0x1FFFF;
    }
    if (b == NB - 1 && t == 0) rp[N] = E;
}

// ---------------- xWs = dinv * (x @ W1), LDS-tiled 4x4 blocking ----------------
__global__ __launch_bounds__(256) void k_gemm1(const float* __restrict__ x,
                                               const float* __restrict__ W1,
                                               const float* __restrict__ dinv,
                                               bf16* __restrict__ xWs, int N) {
    __shared__ __align__(16) float xs[64][66];   // pad 66: write stride 2 banks (free)
    __shared__ __align__(16) float Ws[64][64];
    int tid = threadIdx.x;
    int n0 = blockIdx.x * 64;
    for (int i = tid; i < 4096; i += 256) Ws[i >> 6][i & 63] = W1[i];
    for (int i = tid; i < 4096; i += 256) {
        int node = i >> 6, k = i & 63;
        float v = (n0 + node < N) ? x[(size_t)(n0 + node) * 64 + k] : 0.f;
        xs[k][node] = v;
    }
    __syncthreads();
    int tr = tid >> 4;
    int tc = tid & 15;
    float acc[4][4] = {};
#pragma unroll 8
    for (int k = 0; k < 64; ++k) {
        float2 xa = *(const float2*)&xs[k][tr * 4];
        float2 xb = *(const float2*)&xs[k][tr * 4 + 2];
        float4 wv = *(const float4*)&Ws[k][tc * 4];
        acc[0][0] = fmaf(xa.x, wv.x, acc[0][0]);
        acc[0][1] = fmaf(xa.x, wv.y, acc[0][1]);
        acc[0][2] = fmaf(xa.x, wv.z, acc[0][2]);
        acc[0][3] = fmaf(xa.x, wv.w, acc[0][3]);
        acc[1][0] = fmaf(xa.y, wv.x, acc[1][0]);
        acc[1][1] = fmaf(xa.y, wv.y, acc[1][1]);
        acc[1][2] = fmaf(xa.y, wv.z, acc[1][2]);
        acc[1][3] = fmaf(xa.y, wv.w, acc[1][3]);
        acc[2][0] = fmaf(xb.x, wv.x, acc[2][0]);
        acc[2][1] = fmaf(xb.x, wv.y, acc[2][1]);
        acc[2][2] = fmaf(xb.x, wv.z, acc[2][2]);
        acc[2][3] = fmaf(xb.x, wv.w, acc[2][3]);
        acc[3][0] = fmaf(xb.y, wv.x, acc[3][0]);
        acc[3][1] = fmaf(xb.y, wv.y, acc[3][1]);
        acc[3][2] = fmaf(xb.y, wv.z, acc[3][2]);
        acc[3][3] = fmaf(xb.y, wv.w, acc[3][3]);
    }
#pragma unroll
    for (int i = 0; i < 4; ++i) {
        int node = n0 + tr * 4 + i;
        if (node < N) {
            float di = dinv[node];
            __hip_bfloat162 p0, p1;
            p0.x = __float2bfloat16(di * acc[i][0]);
            p0.y = __float2bfloat16(di * acc[i][1]);
            p1.x = __float2bfloat16(di * acc[i][2]);
            p1.y = __float2bfloat16(di * acc[i][3]);
            __hip_bfloat162* dst2 = (__hip_bfloat162*)&xWs[(size_t)node * 64 + tc * 4];
            dst2[0] = p0;
            dst2[1] = p1;
        }
    }
}

// ---- conv1 gather: 32 lanes/node, bf16x2/lane, 2 nodes per wave ----
__global__ __launch_bounds__(256) void k_gather1(
        const bf16* __restrict__ xWs, const float* __restrict__ dinv,
        const int* __restrict__ rp, const int* __restrict__ col,
        const float* __restrict__ b1, const float* __restrict__ U,
        float* __restrict__ Qs, int N, int E) {
    int wid = blockIdx.x * 8 + (threadIdx.x >> 5);   // node id (8 per block)
    int c = threadIdx.x & 31;                        // channel pair: 2c, 2c+1
    if (wid >= N) return;
    const __hip_bfloat162* xW2 = (const __hip_bfloat162*)xWs;  // [n*32 + c]
    __hip_bfloat162 sv = xW2[(size_t)wid * 32 + c];
    float ax = __bfloat162float(sv.x);
    float ay = __bfloat162float(sv.y);
    int beg = rp[wid], end = rp[wid + 1];
    for (int base = beg; base < end; base += 32) {
        int nn = min(32, end - base);
        int colv = col[min(base + c, E - 1)];
        int jj = 0;
        for (; jj + 8 <= nn; jj += 8) {
            int m0 = __shfl(colv, jj + 0, 32);
            int m1 = __shfl(colv, jj + 1, 32);
            int m2 = __shfl(colv, jj + 2, 32);
            int m3 = __shfl(colv, jj + 3, 32);
            int m4 = __shfl(colv, jj + 4, 32);
            int m5 = __shfl(colv, jj + 5, 32);
            int m6 = __shfl(colv, jj + 6, 32);
            int m7 = __shfl(colv, jj + 7, 32);
            __hip_bfloat162 v0 = xW2[(size_t)m0 * 32 + c];
            __hip_bfloat162 v1 = xW2[(size_t)m1 * 32 + c];
            __hip_bfloat162 v2 = xW2[(size_t)m2 * 32 + c];
            __hip_bfloat162 v3 = xW2[(size_t)m3 * 32 + c];
            __hip_bfloat162 v4 = xW2[(size_t)m4 * 32 + c];
            __hip_bfloat162 v5 = xW2[(size_t)m5 * 32 + c];
            __hip_bfloat162 v6 = xW2[(size_t)m6 * 32 + c];
            __hip_bfloat162 v7 = xW2[(size_t)m7 * 32 + c];
            ax += __bfloat162float(v0.x); ay += __bfloat162float(v0.y);
            ax += __bfloat162float(v1.x); ay += __bfloat162float(v1.y);
            ax += __bfloat162float(v2.x); ay += __bfloat162float(v2.y);
            ax += __bfloat162float(v3.x); ay += __bfloat162float(v3.y);
            ax += __bfloat162float(v4.x); ay += __bfloat162float(v4.y);
            ax += __bfloat162float(v5.x); ay += __bfloat162float(v5.y);
            ax += __bfloat162float(v6.x); ay += __bfloat162float(v6.y);
            ax += __bfloat162float(v7.x); ay += __bfloat162float(v7.y);
        }
        for (; jj < nn; ++jj) {
            int m = __shfl(colv, jj, 32);
            __hip_bfloat162 v = xW2[(size_t)m * 32 + c];
            ax += __bfloat162float(v.x);
            ay += __bfloat162float(v.y);
        }
    }
    float di = dinv[wid];
    float2 b1v = ((const float2*)b1)[c];
    float h0 = fmaxf(fmaf(di, ax, b1v.x), 0.f);
    float h1 = fmaxf(fmaf(di, ay, b1v.y), 0.f);
    float4 Uv = ((const float4*)U)[c];   // {U[2c][0],U[2c][1],U[2c+1][0],U[2c+1][1]}
    float q0 = fmaf(h0, Uv.x, h1 * Uv.z);
    float q1 = fmaf(h0, Uv.y, h1 * Uv.w);
#pragma unroll
    for (int mm = 16; mm; mm >>= 1) {
        q0 += __shfl_xor(q0, mm);        // xor<32 stays within half-wave
        q1 += __shfl_xor(q1, mm);
    }
    if (c == 0) {
        Qs[2 * wid + 0] = di * q0;
        Qs[2 * wid + 1] = di * q1;
    }
}

// ---- conv2 scalar gather (Qs pre-scaled; self-term here) ----
__global__ void k_gather2(const float* __restrict__ dinv, const int* __restrict__ rp,
                          const int* __restrict__ col, const float* __restrict__ Qs,
                          float* __restrict__ P, int N) {
    int n = blockIdx.x * blockDim.x + threadIdx.x;
    if (n >= N) return;
    float2 self = ((const float2*)Qs)[n];
    float p0 = self.x, p1 = self.y;
    int beg = rp[n], end = rp[n + 1];
    int j = beg;
    for (; j + 4 <= end; j += 4) {
        int m0 = col[j + 0], m1 = col[j + 1], m2 = col[j + 2], m3 = col[j + 3];
        float2 q0 = ((const float2*)Qs)[m0];
        float2 q1 = ((const float2*)Qs)[m1];
        float2 q2 = ((const float2*)Qs)[m2];
        float2 q3 = ((const float2*)Qs)[m3];
        p0 += (q0.x + q1.x) + (q2.x + q3.x);
        p1 += (q0.y + q1.y) + (q2.y + q3.y);
    }
    for (; j < end; ++j) {
        float2 q = ((const float2*)Qs)[col[j]];
        p0 += q.x;
        p1 += q.y;
    }
    float di = dinv[n];
    P[2 * n + 0] = di * p0;
    P[2 * n + 1] = di * p1;
}

// ---------------- per-edge epilogue -> fp32 out ----------------
__global__ void k_edge(const int* __restrict__ src, const int* __restrict__ dst,
                       const int* __restrict__ attr, const float* __restrict__ P,
                       const float* __restrict__ E0t, const float* __restrict__ E1t,
                       const float* __restrict__ C, float* __restrict__ out, int E) {
    int e = blockIdx.x * blockDim.x + threadIdx.x;
    if (e >= E) return;
    int s = src[e], d = dst[e];
    float a0 = (float)attr[e];
    float a1 = (float)attr[E + e];
    int i2 = attr[2 * E + e], i3 = attr[3 * E + e];
    const float2* P2 = (const float2*)P;
    float2 ps = P2[s], pd = P2[d];
    float z0 = ps.x - pd.x + a0 * C[2] + a1 * C[4] + E0t[i2 * 2 + 0] + E1t[i3 * 2 + 0] + C[0];
    float z1 = ps.y - pd.y + a0 * C[3] + a1 * C[5] + E0t[i2 * 2 + 1] + E1t[i3 * 2 + 1] + C[1];
    float r0 = fmaxf(z0, 0.f), r1 = fmaxf(z1, 0.f);
    float o0 = r0 * C[6] + r1 * C[8] + C[10];
    float o1 = r0 * C[7] + r1 * C[9] + C[11];
    float m = fmaxf(o0, o1);
    float lse = m + logf(expf(o0 - m) + expf(o1 - m));
    float2 res;
    res.x = o0 - lse;
    res.y = o1 - lse;
    ((float2*)out)[e] = res;
}

extern "C" void kernel_launch(void* const* d_in, const int* in_sizes, int n_in,
                              void* d_out, int out_size, void* d_ws, size_t ws_size,
                              hipStream_t stream) {
    const float* x    = (const float*)d_in[0];
    const int*   ei   = (const int*)d_in[1];
    const int*   ea   = (const int*)d_in[2];
    const float* W1   = (const float*)d_in[3];
    const float* b1   = (const float*)d_in[4];
    const float* W2   = (const float*)d_in[5];
    const float* emb0 = (const float*)d_in[7];
    const float* emb1 = (const float*)d_in[8];
    const float* fcW1 = (const float*)d_in[9];
    const float* fcb1 = (const float*)d_in[10];
    const float* fcW2 = (const float*)d_in[11];
    const float* fcb2 = (const float*)d_in[12];

    const int N = in_sizes[0] / 64;
    const int E = in_sizes[1] / 2;
    const int* src = ei;
    const int* dst = ei + E;
    const int NB = (N + 255) >> 8;                // buckets of 256 nodes (391)
    const int NBB = NB * NBLK;                    // count-matrix size (~100K)
    const int chunk = (E + NBLK - 1) / NBLK;
    const int BS = (NBB + 255) / 256;             // scan chunks == NB (<=512)

    // ws layout (4-byte words), ~15.6 MB:
    char* wsb = (char*)d_ws;
    float* dinv = (float*)wsb;                             // N
    int*   rp   = (int*)(wsb + (size_t)4 * 100352);        // N+1
    int*   cntm = (int*)(wsb + (size_t)4 * 200704);        // NBB
    int*   part = (int*)(wsb + (size_t)4 * 300800);        // 512
    float* U    = (float*)(wsb + (size_t)4 * 301312);      // 128
    float* E0t  = U + 128;                                 // 40
    float* E1t  = E0t + 40;                                // 40
    float* C    = E1t + 40;                                // 12
    float* Qs   = (float*)(wsb + (size_t)4 * 301568);      // 2N
    float* P    = (float*)(wsb + (size_t)4 * 501760);      // 2N
    bf16*  xWs  = (bf16*)(wsb + (size_t)4 * 702464);       // N*64 bf16 (12.8 MB)
    int*   col   = (int*)d_out;                            // E ints (first half)
    int*   pairs = (int*)d_out + E;                        // E ints (second half)
    // col+pairs = 2E ints = exactly out_size floats; k_edge overwrites last.

    kA<<<NBLK, 256, 0, stream>>>(dst, cntm, E, chunk, NB);
    k_mscan1<<<BS, 256, 0, stream>>>(cntm, part, NBB);
    k_scan2small<<<1, 512, 0, stream>>>(part, BS, W2, emb0, emb1, fcW1, fcb1,
                                        fcW2, fcb2, U, E0t, E1t, C);
    kB<<<NBLK, 256, 0, stream>>>(src, dst, cntm, part, pairs, E, chunk, NB);
    kC<<<NB, 256, 0, stream>>>(part, pairs, col, rp, dinv, N, E, NB);
    k_gemm1<<<(N + 63) / 64, 256, 0, stream>>>(x, W1, dinv, xWs, N);
    k_gather1<<<(N + 7) / 8, 256, 0, stream>>>(xWs, dinv, rp, col, b1, U, Qs, N, E);
    k_gather2<<<(N + 255) / 256, 256, 0, stream>>>(dinv, rp, col, Qs, P, N);
    k_edge<<<(E + 255) / 256, 256, 0, stream>>>(src, dst, ea, P, E0t, E1t, C,
                                                (float*)d_out, E);
}